// Round 7
// baseline (3317.947 us; speedup 1.0000x reference)
//
#include <hip/hip_runtime.h>

#define N1 1000000
#define N2 400000
#define N4 150000
#define N8 60000
#define N16 20000

constexpr float BN_EPS = 1e-5f;

__device__ __forceinline__ float lrelu(float x) { return fmaxf(x, 0.1f * x); }
__device__ __forceinline__ void sbar() { __builtin_amdgcn_sched_barrier(0); }

// Fold all BatchNorm params into scale/shift once per call.
// fold: enc0 sc[32],sh[32] @0; encR b: sc[32],sh[32] @64+b*64; dec i: sc[64],sh[64] @320+i*128.
__global__ void k_fold(const float* g0, const float* be0, const float* m0, const float* v0,
                       const float* gR, const float* beR, const float* mR, const float* vR,
                       const float* gD, const float* beD, const float* mD, const float* vD,
                       float* fold) {
  int t = threadIdx.x;
  if (t < 32) {
    float sc = g0[t] * rsqrtf(v0[t] + BN_EPS);
    fold[t] = sc;
    fold[32 + t] = be0[t] - m0[t] * sc;
  }
  if (t < 128) {
    int b = t >> 5, c = t & 31;
    float sc = gR[b * 32 + c] * rsqrtf(vR[b * 32 + c] + BN_EPS);
    fold[64 + b * 64 + c] = sc;
    fold[64 + b * 64 + 32 + c] = beR[b * 32 + c] - mR[b * 32 + c] * sc;
  }
  for (int i = t; i < 320; i += blockDim.x) {
    int b = i >> 6, c = i & 63;
    float sc = gD[b * 64 + c] * rsqrtf(vD[b * 64 + c] + BN_EPS);
    fold[320 + b * 128 + c] = sc;
    fold[320 + b * 128 + 64 + c] = beD[b * 64 + c] - mD[b * 64 + c] * sc;
  }
}

// Build per-segment linked lists. head pre-set to -1. One 4B atomic per row.
__global__ __launch_bounds__(256) void k_fill(const int* __restrict__ idx,
                                              int* head, int* nxt, int n) {
  int i = blockIdx.x * 256 + threadIdx.x;
  if (i < n) nxt[i] = atomicExch(&head[idx[i]], i);
}

// Segment max by chained gather: one wave per segment, one thread per channel.
__global__ __launch_bounds__(256) void k_gmax(
    const float* __restrict__ src, const int* __restrict__ head,
    const int* __restrict__ nxt, float* __restrict__ dst, int nseg) {
  int t = blockIdx.x * 256 + threadIdx.x;
  int seg = t >> 6, ch = t & 63;
  if (seg >= nseg) return;
  float m = -INFINITY;
  for (int p = head[seg]; p >= 0; p = nxt[p])
    m = fmaxf(m, src[(size_t)p * 64 + ch]);
  dst[(size_t)seg * 64 + ch] = (m == -INFINITY) ? 0.0f : m;
}

// ---------------- LDS-tiled fused kernels: 64-row tiles, 256 threads ----------------
// sched_barrier(0) per k-step: stop hipcc from hoisting the whole weight-load
// stream across the k-loop (R5/R6 counters: ~450B/thread paired scratch R/W).

#define FMA44(a, b0, b1v, b2v, b3)                                              \
  do {                                                                          \
    acc[i][0] = fmaf(a.x, b0.x, acc[i][0]); acc[i][1] = fmaf(a.x, b0.y, acc[i][1]); \
    acc[i][2] = fmaf(a.x, b0.z, acc[i][2]); acc[i][3] = fmaf(a.x, b0.w, acc[i][3]); \
    acc[i][0] = fmaf(a.y, b1v.x, acc[i][0]); acc[i][1] = fmaf(a.y, b1v.y, acc[i][1]); \
    acc[i][2] = fmaf(a.y, b1v.z, acc[i][2]); acc[i][3] = fmaf(a.y, b1v.w, acc[i][3]); \
    acc[i][0] = fmaf(a.z, b2v.x, acc[i][0]); acc[i][1] = fmaf(a.z, b2v.y, acc[i][1]); \
    acc[i][2] = fmaf(a.z, b2v.z, acc[i][2]); acc[i][3] = fmaf(a.z, b2v.w, acc[i][3]); \
    acc[i][0] = fmaf(a.w, b3.x, acc[i][0]); acc[i][1] = fmaf(a.w, b3.y, acc[i][1]); \
    acc[i][2] = fmaf(a.w, b3.z, acc[i][2]); acc[i][3] = fmaf(a.w, b3.w, acc[i][3]); \
  } while (0)

// encoder block 0: x[9] -> h[32] (lrelu,BN) -> out[64] (lrelu)
__global__ __attribute__((amdgpu_waves_per_eu(3, 4))) __launch_bounds__(256)
void k_enc0_t(
    const float* __restrict__ x,
    const float* __restrict__ W1, const float* __restrict__ b1,
    const float* __restrict__ fold,
    const float* __restrict__ W2, const float* __restrict__ b2,
    float* __restrict__ out, int n) {
  __shared__ float xS[64 * 12];
  __shared__ float hS[64 * 36];
  int t = threadIdx.x;
  int R = blockIdx.x * 64;

  for (int i = t; i < 576; i += 256) {
    int row = i / 9, col = i - row * 9;
    int gr = R + row; if (gr >= n) gr = n - 1;
    xS[row * 12 + col] = x[(size_t)gr * 9 + col];
  }
  __syncthreads();

  // phase 1: h[64][32], 8 outputs/thread: r0=(t>>3)*2, c0=(t&7)*4, K=9
  {
    int c0 = (t & 7) * 4, r0 = (t >> 3) * 2;
    float4 bias = *(const float4*)(b1 + c0);
    float a0[4] = {bias.x, bias.y, bias.z, bias.w};
    float a1[4] = {bias.x, bias.y, bias.z, bias.w};
    for (int k = 0; k < 9; ++k) {
      float4 b = *(const float4*)(W1 + k * 32 + c0);
      float x0 = xS[r0 * 12 + k], x1 = xS[(r0 + 1) * 12 + k];
      a0[0] = fmaf(x0, b.x, a0[0]); a0[1] = fmaf(x0, b.y, a0[1]);
      a0[2] = fmaf(x0, b.z, a0[2]); a0[3] = fmaf(x0, b.w, a0[3]);
      a1[0] = fmaf(x1, b.x, a1[0]); a1[1] = fmaf(x1, b.y, a1[1]);
      a1[2] = fmaf(x1, b.z, a1[2]); a1[3] = fmaf(x1, b.w, a1[3]);
      sbar();
    }
    float4 sc = *(const float4*)(fold + c0);
    float4 sh = *(const float4*)(fold + 32 + c0);
    hS[r0 * 36 + c0 + 0] = lrelu(a0[0]) * sc.x + sh.x;
    hS[r0 * 36 + c0 + 1] = lrelu(a0[1]) * sc.y + sh.y;
    hS[r0 * 36 + c0 + 2] = lrelu(a0[2]) * sc.z + sh.z;
    hS[r0 * 36 + c0 + 3] = lrelu(a0[3]) * sc.w + sh.w;
    hS[(r0 + 1) * 36 + c0 + 0] = lrelu(a1[0]) * sc.x + sh.x;
    hS[(r0 + 1) * 36 + c0 + 1] = lrelu(a1[1]) * sc.y + sh.y;
    hS[(r0 + 1) * 36 + c0 + 2] = lrelu(a1[2]) * sc.z + sh.z;
    hS[(r0 + 1) * 36 + c0 + 3] = lrelu(a1[3]) * sc.w + sh.w;
  }
  __syncthreads();

  // phase 2: out[64][64] = lrelu(h @ W2 + b2), K=32
  {
    int tx = t & 15, ty = t >> 4;
    int c0 = tx * 4, r0 = ty * 4;
    float4 bias = *(const float4*)(b2 + c0);
    float acc[4][4];
#pragma unroll
    for (int i = 0; i < 4; ++i) {
      acc[i][0] = bias.x; acc[i][1] = bias.y; acc[i][2] = bias.z; acc[i][3] = bias.w;
    }
    for (int k0 = 0; k0 < 32; k0 += 4) {
      float4 b0 = *(const float4*)(W2 + (k0 + 0) * 64 + c0);
      float4 b1v = *(const float4*)(W2 + (k0 + 1) * 64 + c0);
      float4 b2v = *(const float4*)(W2 + (k0 + 2) * 64 + c0);
      float4 b3 = *(const float4*)(W2 + (k0 + 3) * 64 + c0);
#pragma unroll
      for (int i = 0; i < 4; ++i) {
        float4 a = *(const float4*)(hS + (r0 + i) * 36 + k0);
        FMA44(a, b0, b1v, b2v, b3);
      }
      sbar();
    }
#pragma unroll
    for (int i = 0; i < 4; ++i) {
      int gr = R + r0 + i;
      if (gr < n) {
        float4 o;
        o.x = lrelu(acc[i][0]); o.y = lrelu(acc[i][1]);
        o.z = lrelu(acc[i][2]); o.w = lrelu(acc[i][3]);
        *(float4*)(out + (size_t)gr * 64 + c0) = o;
      }
    }
  }
}

// encoder blocks 1..4: in[64] -> h[32] (lrelu,BN) -> out[64] (lrelu)
__global__ __attribute__((amdgpu_waves_per_eu(3, 4))) __launch_bounds__(256)
void k_encR_t(
    const float* __restrict__ xin,
    const float* __restrict__ W1, const float* __restrict__ b1,
    const float* __restrict__ fold,
    const float* __restrict__ W2, const float* __restrict__ b2,
    float* __restrict__ out, int n) {
  __shared__ float xS[64 * 68];
  __shared__ float hS[64 * 36];
  int t = threadIdx.x;
  int R = blockIdx.x * 64;

  for (int f = t; f < 1024; f += 256) {  // flat-coalesced staging
    int row = f >> 4, seg = (f & 15) * 4;
    int gr = R + row; if (gr >= n) gr = n - 1;
    *(float4*)(xS + row * 68 + seg) = *(const float4*)(xin + (size_t)gr * 64 + seg);
  }
  __syncthreads();

  // phase 1: h[64][32], K=64, 8 outputs/thread
  {
    int c0 = (t & 7) * 4, r0 = (t >> 3) * 2;
    float4 bias = *(const float4*)(b1 + c0);
    float a0[4] = {bias.x, bias.y, bias.z, bias.w};
    float a1[4] = {bias.x, bias.y, bias.z, bias.w};
    for (int k0 = 0; k0 < 64; k0 += 4) {
      float4 b0 = *(const float4*)(W1 + (k0 + 0) * 32 + c0);
      float4 b1v = *(const float4*)(W1 + (k0 + 1) * 32 + c0);
      float4 b2v = *(const float4*)(W1 + (k0 + 2) * 32 + c0);
      float4 b3 = *(const float4*)(W1 + (k0 + 3) * 32 + c0);
      float4 x0 = *(const float4*)(xS + r0 * 68 + k0);
      float4 x1 = *(const float4*)(xS + (r0 + 1) * 68 + k0);
      a0[0] = fmaf(x0.x, b0.x, a0[0]); a0[1] = fmaf(x0.x, b0.y, a0[1]);
      a0[2] = fmaf(x0.x, b0.z, a0[2]); a0[3] = fmaf(x0.x, b0.w, a0[3]);
      a0[0] = fmaf(x0.y, b1v.x, a0[0]); a0[1] = fmaf(x0.y, b1v.y, a0[1]);
      a0[2] = fmaf(x0.y, b1v.z, a0[2]); a0[3] = fmaf(x0.y, b1v.w, a0[3]);
      a0[0] = fmaf(x0.z, b2v.x, a0[0]); a0[1] = fmaf(x0.z, b2v.y, a0[1]);
      a0[2] = fmaf(x0.z, b2v.z, a0[2]); a0[3] = fmaf(x0.z, b2v.w, a0[3]);
      a0[0] = fmaf(x0.w, b3.x, a0[0]); a0[1] = fmaf(x0.w, b3.y, a0[1]);
      a0[2] = fmaf(x0.w, b3.z, a0[2]); a0[3] = fmaf(x0.w, b3.w, a0[3]);
      a1[0] = fmaf(x1.x, b0.x, a1[0]); a1[1] = fmaf(x1.x, b0.y, a1[1]);
      a1[2] = fmaf(x1.x, b0.z, a1[2]); a1[3] = fmaf(x1.x, b0.w, a1[3]);
      a1[0] = fmaf(x1.y, b1v.x, a1[0]); a1[1] = fmaf(x1.y, b1v.y, a1[1]);
      a1[2] = fmaf(x1.y, b1v.z, a1[2]); a1[3] = fmaf(x1.y, b1v.w, a1[3]);
      a1[0] = fmaf(x1.z, b2v.x, a1[0]); a1[1] = fmaf(x1.z, b2v.y, a1[1]);
      a1[2] = fmaf(x1.z, b2v.z, a1[2]); a1[3] = fmaf(x1.z, b2v.w, a1[3]);
      a1[0] = fmaf(x1.w, b3.x, a1[0]); a1[1] = fmaf(x1.w, b3.y, a1[1]);
      a1[2] = fmaf(x1.w, b3.z, a1[2]); a1[3] = fmaf(x1.w, b3.w, a1[3]);
      sbar();
    }
    float4 sc = *(const float4*)(fold + c0);
    float4 sh = *(const float4*)(fold + 32 + c0);
    hS[r0 * 36 + c0 + 0] = lrelu(a0[0]) * sc.x + sh.x;
    hS[r0 * 36 + c0 + 1] = lrelu(a0[1]) * sc.y + sh.y;
    hS[r0 * 36 + c0 + 2] = lrelu(a0[2]) * sc.z + sh.z;
    hS[r0 * 36 + c0 + 3] = lrelu(a0[3]) * sc.w + sh.w;
    hS[(r0 + 1) * 36 + c0 + 0] = lrelu(a1[0]) * sc.x + sh.x;
    hS[(r0 + 1) * 36 + c0 + 1] = lrelu(a1[1]) * sc.y + sh.y;
    hS[(r0 + 1) * 36 + c0 + 2] = lrelu(a1[2]) * sc.z + sh.z;
    hS[(r0 + 1) * 36 + c0 + 3] = lrelu(a1[3]) * sc.w + sh.w;
  }
  __syncthreads();

  // phase 2: out = lrelu(h @ W2 + b2), K=32
  {
    int tx = t & 15, ty = t >> 4;
    int c0 = tx * 4, r0 = ty * 4;
    float4 bias = *(const float4*)(b2 + c0);
    float acc[4][4];
#pragma unroll
    for (int i = 0; i < 4; ++i) {
      acc[i][0] = bias.x; acc[i][1] = bias.y; acc[i][2] = bias.z; acc[i][3] = bias.w;
    }
    for (int k0 = 0; k0 < 32; k0 += 4) {
      float4 b0 = *(const float4*)(W2 + (k0 + 0) * 64 + c0);
      float4 b1v = *(const float4*)(W2 + (k0 + 1) * 64 + c0);
      float4 b2v = *(const float4*)(W2 + (k0 + 2) * 64 + c0);
      float4 b3 = *(const float4*)(W2 + (k0 + 3) * 64 + c0);
#pragma unroll
      for (int i = 0; i < 4; ++i) {
        float4 a = *(const float4*)(hS + (r0 + i) * 36 + k0);
        FMA44(a, b0, b1v, b2v, b3);
      }
      sbar();
    }
#pragma unroll
    for (int i = 0; i < 4; ++i) {
      int gr = R + r0 + i;
      if (gr < n) {
        float4 o;
        o.x = lrelu(acc[i][0]); o.y = lrelu(acc[i][1]);
        o.z = lrelu(acc[i][2]); o.w = lrelu(acc[i][3]);
        *(float4*)(out + (size_t)gr * 64 + c0) = o;
      }
    }
  }
}

// decoder block, in place on `inout`:
//   skip = lrelu(cur @ mlpW + mlpb); out = lrelu(BN([skip,last] @ decW + decb))
// skip reuses curS (barrier-separated) -> 35 KB LDS.
__global__ __attribute__((amdgpu_waves_per_eu(3, 4))) __launch_bounds__(256)
void k_dec_t(
    float* inout, const float* __restrict__ lastbuf, const int* __restrict__ idx,
    const float* __restrict__ mlpW, const float* __restrict__ mlpb,
    const float* __restrict__ decW, const float* __restrict__ decb,
    const float* __restrict__ fold, int n) {
  __shared__ float curS[64 * 68];
  __shared__ float lastS[64 * 68];
  int t = threadIdx.x;
  int R = blockIdx.x * 64;

  for (int f = t; f < 1024; f += 256) {  // flat-coalesced staging
    int row = f >> 4, seg = (f & 15) * 4;
    int gr = R + row; if (gr >= n) gr = n - 1;
    *(float4*)(curS + row * 68 + seg) = *(const float4*)(inout + (size_t)gr * 64 + seg);
    int lr = idx ? idx[gr] : gr;
    *(float4*)(lastS + row * 68 + seg) = *(const float4*)(lastbuf + (size_t)lr * 64 + seg);
  }
  __syncthreads();

  int tx = t & 15, ty = t >> 4;
  int c0 = tx * 4, r0 = ty * 4;

  // phase 1: skip = lrelu(cur @ mlpW + mlpb), K=64
  float acc[4][4];
  {
    float4 bias = *(const float4*)(mlpb + c0);
#pragma unroll
    for (int i = 0; i < 4; ++i) {
      acc[i][0] = bias.x; acc[i][1] = bias.y; acc[i][2] = bias.z; acc[i][3] = bias.w;
    }
    for (int k0 = 0; k0 < 64; k0 += 4) {
      float4 b0 = *(const float4*)(mlpW + (k0 + 0) * 64 + c0);
      float4 b1v = *(const float4*)(mlpW + (k0 + 1) * 64 + c0);
      float4 b2v = *(const float4*)(mlpW + (k0 + 2) * 64 + c0);
      float4 b3 = *(const float4*)(mlpW + (k0 + 3) * 64 + c0);
#pragma unroll
      for (int i = 0; i < 4; ++i) {
        float4 a = *(const float4*)(curS + (r0 + i) * 68 + k0);
        FMA44(a, b0, b1v, b2v, b3);
      }
      sbar();
    }
  }
  __syncthreads();  // all phase-1 reads of curS done
#pragma unroll
  for (int i = 0; i < 4; ++i) {
    curS[(r0 + i) * 68 + c0 + 0] = lrelu(acc[i][0]);
    curS[(r0 + i) * 68 + c0 + 1] = lrelu(acc[i][1]);
    curS[(r0 + i) * 68 + c0 + 2] = lrelu(acc[i][2]);
    curS[(r0 + i) * 68 + c0 + 3] = lrelu(acc[i][3]);
  }
  __syncthreads();

  // phase 2: out = BN(skip @ decW[0:64] + last @ decW[64:128] + decb), lrelu
  {
    float4 bias = *(const float4*)(decb + c0);
#pragma unroll
    for (int i = 0; i < 4; ++i) {
      acc[i][0] = bias.x; acc[i][1] = bias.y; acc[i][2] = bias.z; acc[i][3] = bias.w;
    }
    for (int k0 = 0; k0 < 64; k0 += 4) {
      float4 b0 = *(const float4*)(decW + (k0 + 0) * 64 + c0);
      float4 b1v = *(const float4*)(decW + (k0 + 1) * 64 + c0);
      float4 b2v = *(const float4*)(decW + (k0 + 2) * 64 + c0);
      float4 b3 = *(const float4*)(decW + (k0 + 3) * 64 + c0);
#pragma unroll
      for (int i = 0; i < 4; ++i) {
        float4 a = *(const float4*)(curS + (r0 + i) * 68 + k0);
        FMA44(a, b0, b1v, b2v, b3);
      }
      sbar();
    }
    for (int k0 = 0; k0 < 64; k0 += 4) {
      float4 b0 = *(const float4*)(decW + (64 + k0 + 0) * 64 + c0);
      float4 b1v = *(const float4*)(decW + (64 + k0 + 1) * 64 + c0);
      float4 b2v = *(const float4*)(decW + (64 + k0 + 2) * 64 + c0);
      float4 b3 = *(const float4*)(decW + (64 + k0 + 3) * 64 + c0);
#pragma unroll
      for (int i = 0; i < 4; ++i) {
        float4 a = *(const float4*)(lastS + (r0 + i) * 68 + k0);
        FMA44(a, b0, b1v, b2v, b3);
      }
      sbar();
    }
    float4 sc = *(const float4*)(fold + c0);
    float4 sh = *(const float4*)(fold + 64 + c0);
#pragma unroll
    for (int i = 0; i < 4; ++i) {
      int gr = R + r0 + i;
      if (gr < n) {
        float4 o;
        o.x = lrelu(acc[i][0] * sc.x + sh.x);
        o.y = lrelu(acc[i][1] * sc.y + sh.y);
        o.z = lrelu(acc[i][2] * sc.z + sh.z);
        o.w = lrelu(acc[i][3] * sc.w + sh.w);
        *(float4*)(inout + (size_t)gr * 64 + c0) = o;
      }
    }
  }
}

extern "C" void kernel_launch(void* const* d_in, const int* in_sizes, int n_in,
                              void* d_out, int out_size, void* d_ws, size_t ws_size,
                              hipStream_t stream) {
  const float* pt   = (const float*)d_in[0];
  const int* inv2   = (const int*)d_in[1];
  const int* inv4   = (const int*)d_in[2];
  const int* inv8   = (const int*)d_in[3];
  const int* inv16  = (const int*)d_in[4];
  const float* e0W1 = (const float*)d_in[5];
  const float* e0b1 = (const float*)d_in[6];
  const float* e0g  = (const float*)d_in[7];
  const float* e0be = (const float*)d_in[8];
  const float* e0m  = (const float*)d_in[9];
  const float* e0v  = (const float*)d_in[10];
  const float* e0W2 = (const float*)d_in[11];
  const float* e0b2 = (const float*)d_in[12];
  const float* eRW1 = (const float*)d_in[13];
  const float* eRb1 = (const float*)d_in[14];
  const float* eRg  = (const float*)d_in[15];
  const float* eRbe = (const float*)d_in[16];
  const float* eRm  = (const float*)d_in[17];
  const float* eRv  = (const float*)d_in[18];
  const float* eRW2 = (const float*)d_in[19];
  const float* eRb2 = (const float*)d_in[20];
  const float* mlpW = (const float*)d_in[21];
  const float* mlpb = (const float*)d_in[22];
  const float* decW = (const float*)d_in[23];
  const float* decb = (const float*)d_in[24];
  const float* decg = (const float*)d_in[25];
  const float* decbe= (const float*)d_in[26];
  const float* decm = (const float*)d_in[27];
  const float* decv = (const float*)d_in[28];

  float* s1 = (float*)d_out;
  float* s2 = s1 + (size_t)N1 * 64;
  float* s3 = s2 + (size_t)N2 * 64;
  float* s4 = s3 + (size_t)N4 * 64;
  float* s5 = s4 + (size_t)N8 * 64;

  // workspace: fold | oA (N2*64 f) | oB (N4*64 f) | head (N2 i) | nxt (N1 i)
  float* fold = (float*)d_ws;
  float* oA   = fold + 1024;
  float* oB   = oA + (size_t)N2 * 64;
  int* head   = (int*)(oB + (size_t)N4 * 64);
  int* nxt    = head + N2;

  k_fold<<<1, 320, 0, stream>>>(e0g, e0be, e0m, e0v, eRg, eRbe, eRm, eRv,
                                decg, decbe, decm, decv, fold);

  // ---- level 1: enc0 on N1, pool -> oA [N2] ----
  hipMemsetAsync(head, 0xFF, (size_t)N2 * 4, stream);
  k_fill<<<(N1 + 255) / 256, 256, 0, stream>>>(inv2, head, nxt, N1);
  k_enc0_t<<<(N1 + 63) / 64, 256, 0, stream>>>(pt, e0W1, e0b1, fold, e0W2, e0b2, s1, N1);
  k_gmax<<<((size_t)N2 * 64 + 255) / 256, 256, 0, stream>>>(s1, head, nxt, oA, N2);

  // ---- level 2: encR[0] on N2, pool -> oB [N4] ----
  hipMemsetAsync(head, 0xFF, (size_t)N4 * 4, stream);
  k_fill<<<(N2 + 255) / 256, 256, 0, stream>>>(inv4, head, nxt, N2);
  k_encR_t<<<(N2 + 63) / 64, 256, 0, stream>>>(oA, eRW1 + 0 * 2048, eRb1 + 0 * 32,
                                               fold + 64 + 0 * 64, eRW2 + 0 * 2048,
                                               eRb2 + 0 * 64, s2, N2);
  k_gmax<<<((size_t)N4 * 64 + 255) / 256, 256, 0, stream>>>(s2, head, nxt, oB, N4);

  // ---- level 3: encR[1] on N4, pool -> oA [N8] ----
  hipMemsetAsync(head, 0xFF, (size_t)N8 * 4, stream);
  k_fill<<<(N4 + 255) / 256, 256, 0, stream>>>(inv8, head, nxt, N4);
  k_encR_t<<<(N4 + 63) / 64, 256, 0, stream>>>(oB, eRW1 + 1 * 2048, eRb1 + 1 * 32,
                                               fold + 64 + 1 * 64, eRW2 + 1 * 2048,
                                               eRb2 + 1 * 64, s3, N4);
  k_gmax<<<((size_t)N8 * 64 + 255) / 256, 256, 0, stream>>>(s3, head, nxt, oA, N8);

  // ---- level 4: encR[2] on N8, pool -> oB [N16] ----
  hipMemsetAsync(head, 0xFF, (size_t)N16 * 4, stream);
  k_fill<<<(N8 + 255) / 256, 256, 0, stream>>>(inv16, head, nxt, N8);
  k_encR_t<<<(N8 + 63) / 64, 256, 0, stream>>>(oA, eRW1 + 2 * 2048, eRb1 + 2 * 32,
                                               fold + 64 + 2 * 64, eRW2 + 2 * 2048,
                                               eRb2 + 2 * 64, s4, N8);
  k_gmax<<<((size_t)N16 * 64 + 255) / 256, 256, 0, stream>>>(s4, head, nxt, oB, N16);

  // ---- level 5: encR[3] on N16 ----
  k_encR_t<<<(N16 + 63) / 64, 256, 0, stream>>>(oB, eRW1 + 3 * 2048, eRb1 + 3 * 32,
                                                fold + 64 + 3 * 64, eRW2 + 3 * 2048,
                                                eRb2 + 3 * 64, s5, N16);

  // ---- decoders (in place, top-down) ----
  k_dec_t<<<(N16 + 63) / 64, 256, 0, stream>>>(s5, s5, nullptr, mlpW + 0 * 4096, mlpb + 0 * 64,
                                               decW + 0 * 8192, decb + 0 * 64,
                                               fold + 320 + 0 * 128, N16);
  k_dec_t<<<(N8 + 63) / 64, 256, 0, stream>>>(s4, s5, inv16, mlpW + 1 * 4096, mlpb + 1 * 64,
                                              decW + 1 * 8192, decb + 1 * 64,
                                              fold + 320 + 1 * 128, N8);
  k_dec_t<<<(N4 + 63) / 64, 256, 0, stream>>>(s3, s4, inv8, mlpW + 2 * 4096, mlpb + 2 * 64,
                                              decW + 2 * 8192, decb + 2 * 64,
                                              fold + 320 + 2 * 128, N4);
  k_dec_t<<<(N2 + 63) / 64, 256, 0, stream>>>(s2, s3, inv4, mlpW + 3 * 4096, mlpb + 3 * 64,
                                              decW + 3 * 8192, decb + 3 * 64,
                                              fold + 320 + 3 * 128, N2);
  k_dec_t<<<(N1 + 63) / 64, 256, 0, stream>>>(s1, s2, inv2, mlpW + 4 * 4096, mlpb + 4 * 64,
                                              decW + 4 * 8192, decb + 4 * 64,
                                              fold + 320 + 4 * 128, N1);
}

// Round 8
// 1482.935 us; speedup vs baseline: 2.2374x; 2.2374x over previous
//
#include <hip/hip_runtime.h>

#define N1 1000000
#define N2 400000
#define N4 150000
#define N8 60000
#define N16 20000

constexpr float BN_EPS = 1e-5f;

__device__ __forceinline__ float lrelu(float x) { return fmaxf(x, 0.1f * x); }

// Fold all BatchNorm params into scale/shift once per call.
// fold: enc0 sc[32],sh[32] @0; encR b: sc[32],sh[32] @64+b*64; dec i: sc[64],sh[64] @320+i*128.
__global__ void k_fold(const float* g0, const float* be0, const float* m0, const float* v0,
                       const float* gR, const float* beR, const float* mR, const float* vR,
                       const float* gD, const float* beD, const float* mD, const float* vD,
                       float* fold) {
  int t = threadIdx.x;
  if (t < 32) {
    float sc = g0[t] * rsqrtf(v0[t] + BN_EPS);
    fold[t] = sc;
    fold[32 + t] = be0[t] - m0[t] * sc;
  }
  if (t < 128) {
    int b = t >> 5, c = t & 31;
    float sc = gR[b * 32 + c] * rsqrtf(vR[b * 32 + c] + BN_EPS);
    fold[64 + b * 64 + c] = sc;
    fold[64 + b * 64 + 32 + c] = beR[b * 32 + c] - mR[b * 32 + c] * sc;
  }
  for (int i = t; i < 320; i += blockDim.x) {
    int b = i >> 6, c = i & 63;
    float sc = gD[b * 64 + c] * rsqrtf(vD[b * 64 + c] + BN_EPS);
    fold[320 + b * 128 + c] = sc;
    fold[320 + b * 128 + 64 + c] = beD[b * 64 + c] - mD[b * 64 + c] * sc;
  }
}

// Build per-segment linked lists. head pre-set to -1. One 4B atomic per row.
__global__ __launch_bounds__(256) void k_fill(const int* __restrict__ idx,
                                              int* head, int* nxt, int n) {
  int i = blockIdx.x * 256 + threadIdx.x;
  if (i < n) nxt[i] = atomicExch(&head[idx[i]], i);
}

// Segment max by chained gather: one wave per segment, one thread per channel.
__global__ __launch_bounds__(256) void k_gmax(
    const float* __restrict__ src, const int* __restrict__ head,
    const int* __restrict__ nxt, float* __restrict__ dst, int nseg) {
  int t = blockIdx.x * 256 + threadIdx.x;
  int seg = t >> 6, ch = t & 63;
  if (seg >= nseg) return;
  float m = -INFINITY;
  for (int p = head[seg]; p >= 0; p = nxt[p])
    m = fmaxf(m, src[(size_t)p * 64 + ch]);
  dst[(size_t)seg * 64 + ch] = (m == -INFINITY) ? 0.0f : m;
}

// ---------------- scalar-weight GEMM kernels ----------------
// lane = output row (64 rows/block), wave w = 16-col (or 8-col) slice.
// Weights are wave-uniform -> scalar loads (readfirstlane'd wave id), inputs
// come from stride-65/stride-9/stride-33 LDS (odd dword stride: 2 lanes/bank,
// free). Per-thread state ~30-50 VGPRs -> structurally no spill.

// encoder block 0: x[9] -> h[32] (lrelu,BN) -> out[64] (lrelu)
__global__ __launch_bounds__(256) void k_enc0_s(
    const float* __restrict__ x,
    const float* __restrict__ W1, const float* __restrict__ b1,
    const float* __restrict__ fold,
    const float* __restrict__ W2, const float* __restrict__ b2,
    float* __restrict__ out, int n) {
  __shared__ float xS[64 * 9];
  __shared__ float hS[64 * 33];
  int t = threadIdx.x;
  int lane = t & 63;
  int w = __builtin_amdgcn_readfirstlane(t >> 6);
  int R = blockIdx.x * 64;

  // flat coalesced stage of x rows (clamped at tail)
  {
    size_t lim = (size_t)n * 9 - 1;
    for (int i = t; i < 576; i += 256) {
      size_t gi = (size_t)R * 9 + i;
      if (gi > lim) gi = lim;
      xS[i] = x[gi];
    }
  }
  __syncthreads();

  // phase 1: h cols 8w..8w+7, K=9
  {
    const float* W1p = W1 + w * 8;
    float acc[8];
#pragma unroll
    for (int c = 0; c < 8; ++c) acc[c] = b1[w * 8 + c];
    for (int k = 0; k < 9; ++k) {
      float a = xS[lane * 9 + k];
#pragma unroll
      for (int c = 0; c < 8; ++c) acc[c] = fmaf(a, W1p[k * 32 + c], acc[c]);
    }
#pragma unroll
    for (int c = 0; c < 8; ++c) {
      float sc = fold[w * 8 + c], sh = fold[32 + w * 8 + c];
      hS[lane * 33 + w * 8 + c] = lrelu(acc[c]) * sc + sh;
    }
  }
  __syncthreads();

  // phase 2: out cols 16w..16w+15, K=32
  {
    const float* W2p = W2 + w * 16;
    float o[16];
#pragma unroll
    for (int c = 0; c < 16; ++c) o[c] = b2[w * 16 + c];
    for (int k = 0; k < 32; ++k) {
      float a = hS[lane * 33 + k];
#pragma unroll
      for (int c = 0; c < 16; ++c) o[c] = fmaf(a, W2p[k * 64 + c], o[c]);
    }
    int gr = R + lane;
    if (gr < n) {
      float* op = out + (size_t)gr * 64 + w * 16;
#pragma unroll
      for (int c = 0; c < 16; ++c) op[c] = lrelu(o[c]);
    }
  }
}

// encoder blocks 1..4: in[64] -> h[32] (lrelu,BN) -> out[64] (lrelu)
__global__ __launch_bounds__(256) void k_encR_s(
    const float* __restrict__ xin,
    const float* __restrict__ W1, const float* __restrict__ b1,
    const float* __restrict__ fold,
    const float* __restrict__ W2, const float* __restrict__ b2,
    float* __restrict__ out, int n) {
  __shared__ float inS[64 * 65];
  __shared__ float hS[64 * 33];
  int t = threadIdx.x;
  int lane = t & 63;
  int w = __builtin_amdgcn_readfirstlane(t >> 6);
  int R = blockIdx.x * 64;

  for (int f = t; f < 1024; f += 256) {
    int row = f >> 4, c4 = (f & 15) << 2;
    int gr = R + row; if (gr >= n) gr = n - 1;
    float4 v = *(const float4*)(xin + (size_t)gr * 64 + c4);
    inS[row * 65 + c4 + 0] = v.x; inS[row * 65 + c4 + 1] = v.y;
    inS[row * 65 + c4 + 2] = v.z; inS[row * 65 + c4 + 3] = v.w;
  }
  __syncthreads();

  // phase 1: h cols 8w..8w+7, K=64
  {
    const float* W1p = W1 + w * 8;
    float acc[8];
#pragma unroll
    for (int c = 0; c < 8; ++c) acc[c] = b1[w * 8 + c];
    for (int k = 0; k < 64; ++k) {
      float a = inS[lane * 65 + k];
#pragma unroll
      for (int c = 0; c < 8; ++c) acc[c] = fmaf(a, W1p[k * 32 + c], acc[c]);
    }
#pragma unroll
    for (int c = 0; c < 8; ++c) {
      float sc = fold[w * 8 + c], sh = fold[32 + w * 8 + c];
      hS[lane * 33 + w * 8 + c] = lrelu(acc[c]) * sc + sh;
    }
  }
  __syncthreads();

  // phase 2: out cols 16w..16w+15, K=32
  {
    const float* W2p = W2 + w * 16;
    float o[16];
#pragma unroll
    for (int c = 0; c < 16; ++c) o[c] = b2[w * 16 + c];
    for (int k = 0; k < 32; ++k) {
      float a = hS[lane * 33 + k];
#pragma unroll
      for (int c = 0; c < 16; ++c) o[c] = fmaf(a, W2p[k * 64 + c], o[c]);
    }
    int gr = R + lane;
    if (gr < n) {
      float* op = out + (size_t)gr * 64 + w * 16;
#pragma unroll
      for (int c = 0; c < 16; ++c) op[c] = lrelu(o[c]);
    }
  }
}

// decoder block, in place on `inout`:
//   skip = lrelu(cur @ mlpW + mlpb); out = lrelu(BN([skip,last] @ decW + decb))
// skip overwrites curS (barrier-separated).
__global__ __launch_bounds__(256) void k_dec_s(
    float* inout, const float* __restrict__ lastbuf, const int* __restrict__ idx,
    const float* __restrict__ mlpW, const float* __restrict__ mlpb,
    const float* __restrict__ decW, const float* __restrict__ decb,
    const float* __restrict__ fold, int n) {
  __shared__ float curS[64 * 65];
  __shared__ float lastS[64 * 65];
  int t = threadIdx.x;
  int lane = t & 63;
  int w = __builtin_amdgcn_readfirstlane(t >> 6);
  int R = blockIdx.x * 64;

  for (int f = t; f < 1024; f += 256) {
    int row = f >> 4, c4 = (f & 15) << 2;
    int gr = R + row; if (gr >= n) gr = n - 1;
    float4 v = *(const float4*)(inout + (size_t)gr * 64 + c4);
    curS[row * 65 + c4 + 0] = v.x; curS[row * 65 + c4 + 1] = v.y;
    curS[row * 65 + c4 + 2] = v.z; curS[row * 65 + c4 + 3] = v.w;
    int lr = idx ? idx[gr] : gr;
    float4 u = *(const float4*)(lastbuf + (size_t)lr * 64 + c4);
    lastS[row * 65 + c4 + 0] = u.x; lastS[row * 65 + c4 + 1] = u.y;
    lastS[row * 65 + c4 + 2] = u.z; lastS[row * 65 + c4 + 3] = u.w;
  }
  __syncthreads();

  // phase 1: skip cols 16w..16w+15, K=64
  float sk[16];
  {
    const float* Mp = mlpW + w * 16;
#pragma unroll
    for (int c = 0; c < 16; ++c) sk[c] = mlpb[w * 16 + c];
    for (int k = 0; k < 64; ++k) {
      float a = curS[lane * 65 + k];
#pragma unroll
      for (int c = 0; c < 16; ++c) sk[c] = fmaf(a, Mp[k * 64 + c], sk[c]);
    }
  }
  __syncthreads();  // all reads of curS done
#pragma unroll
  for (int c = 0; c < 16; ++c)
    curS[lane * 65 + w * 16 + c] = lrelu(sk[c]);
  __syncthreads();

  // phase 2: out cols 16w..16w+15, K=128 (skip rows then last rows)
  {
    const float* Dp = decW + w * 16;
    float o[16];
#pragma unroll
    for (int c = 0; c < 16; ++c) o[c] = decb[w * 16 + c];
    for (int k = 0; k < 64; ++k) {
      float a = curS[lane * 65 + k];
#pragma unroll
      for (int c = 0; c < 16; ++c) o[c] = fmaf(a, Dp[k * 64 + c], o[c]);
    }
    for (int k = 0; k < 64; ++k) {
      float a = lastS[lane * 65 + k];
#pragma unroll
      for (int c = 0; c < 16; ++c) o[c] = fmaf(a, Dp[(64 + k) * 64 + c], o[c]);
    }
    int gr = R + lane;
    if (gr < n) {
      float* op = inout + (size_t)gr * 64 + w * 16;
#pragma unroll
      for (int c = 0; c < 16; ++c) {
        float sc = fold[w * 16 + c], sh = fold[64 + w * 16 + c];
        op[c] = lrelu(o[c] * sc + sh);
      }
    }
  }
}

extern "C" void kernel_launch(void* const* d_in, const int* in_sizes, int n_in,
                              void* d_out, int out_size, void* d_ws, size_t ws_size,
                              hipStream_t stream) {
  const float* pt   = (const float*)d_in[0];
  const int* inv2   = (const int*)d_in[1];
  const int* inv4   = (const int*)d_in[2];
  const int* inv8   = (const int*)d_in[3];
  const int* inv16  = (const int*)d_in[4];
  const float* e0W1 = (const float*)d_in[5];
  const float* e0b1 = (const float*)d_in[6];
  const float* e0g  = (const float*)d_in[7];
  const float* e0be = (const float*)d_in[8];
  const float* e0m  = (const float*)d_in[9];
  const float* e0v  = (const float*)d_in[10];
  const float* e0W2 = (const float*)d_in[11];
  const float* e0b2 = (const float*)d_in[12];
  const float* eRW1 = (const float*)d_in[13];
  const float* eRb1 = (const float*)d_in[14];
  const float* eRg  = (const float*)d_in[15];
  const float* eRbe = (const float*)d_in[16];
  const float* eRm  = (const float*)d_in[17];
  const float* eRv  = (const float*)d_in[18];
  const float* eRW2 = (const float*)d_in[19];
  const float* eRb2 = (const float*)d_in[20];
  const float* mlpW = (const float*)d_in[21];
  const float* mlpb = (const float*)d_in[22];
  const float* decW = (const float*)d_in[23];
  const float* decb = (const float*)d_in[24];
  const float* decg = (const float*)d_in[25];
  const float* decbe= (const float*)d_in[26];
  const float* decm = (const float*)d_in[27];
  const float* decv = (const float*)d_in[28];

  float* s1 = (float*)d_out;
  float* s2 = s1 + (size_t)N1 * 64;
  float* s3 = s2 + (size_t)N2 * 64;
  float* s4 = s3 + (size_t)N4 * 64;
  float* s5 = s4 + (size_t)N8 * 64;

  // workspace: fold | oA (N2*64 f) | oB (N4*64 f) | head (N2 i) | nxt (N1 i)
  float* fold = (float*)d_ws;
  float* oA   = fold + 1024;
  float* oB   = oA + (size_t)N2 * 64;
  int* head   = (int*)(oB + (size_t)N4 * 64);
  int* nxt    = head + N2;

  k_fold<<<1, 320, 0, stream>>>(e0g, e0be, e0m, e0v, eRg, eRbe, eRm, eRv,
                                decg, decbe, decm, decv, fold);

  // ---- level 1: enc0 on N1, pool -> oA [N2] ----
  hipMemsetAsync(head, 0xFF, (size_t)N2 * 4, stream);
  k_fill<<<(N1 + 255) / 256, 256, 0, stream>>>(inv2, head, nxt, N1);
  k_enc0_s<<<(N1 + 63) / 64, 256, 0, stream>>>(pt, e0W1, e0b1, fold, e0W2, e0b2, s1, N1);
  k_gmax<<<((size_t)N2 * 64 + 255) / 256, 256, 0, stream>>>(s1, head, nxt, oA, N2);

  // ---- level 2: encR[0] on N2, pool -> oB [N4] ----
  hipMemsetAsync(head, 0xFF, (size_t)N4 * 4, stream);
  k_fill<<<(N2 + 255) / 256, 256, 0, stream>>>(inv4, head, nxt, N2);
  k_encR_s<<<(N2 + 63) / 64, 256, 0, stream>>>(oA, eRW1 + 0 * 2048, eRb1 + 0 * 32,
                                               fold + 64 + 0 * 64, eRW2 + 0 * 2048,
                                               eRb2 + 0 * 64, s2, N2);
  k_gmax<<<((size_t)N4 * 64 + 255) / 256, 256, 0, stream>>>(s2, head, nxt, oB, N4);

  // ---- level 3: encR[1] on N4, pool -> oA [N8] ----
  hipMemsetAsync(head, 0xFF, (size_t)N8 * 4, stream);
  k_fill<<<(N4 + 255) / 256, 256, 0, stream>>>(inv8, head, nxt, N4);
  k_encR_s<<<(N4 + 63) / 64, 256, 0, stream>>>(oB, eRW1 + 1 * 2048, eRb1 + 1 * 32,
                                               fold + 64 + 1 * 64, eRW2 + 1 * 2048,
                                               eRb2 + 1 * 64, s3, N4);
  k_gmax<<<((size_t)N8 * 64 + 255) / 256, 256, 0, stream>>>(s3, head, nxt, oA, N8);

  // ---- level 4: encR[2] on N8, pool -> oB [N16] ----
  hipMemsetAsync(head, 0xFF, (size_t)N16 * 4, stream);
  k_fill<<<(N8 + 255) / 256, 256, 0, stream>>>(inv16, head, nxt, N8);
  k_encR_s<<<(N8 + 63) / 64, 256, 0, stream>>>(oA, eRW1 + 2 * 2048, eRb1 + 2 * 32,
                                               fold + 64 + 2 * 64, eRW2 + 2 * 2048,
                                               eRb2 + 2 * 64, s4, N8);
  k_gmax<<<((size_t)N16 * 64 + 255) / 256, 256, 0, stream>>>(s4, head, nxt, oB, N16);

  // ---- level 5: encR[3] on N16 ----
  k_encR_s<<<(N16 + 63) / 64, 256, 0, stream>>>(oB, eRW1 + 3 * 2048, eRb1 + 3 * 32,
                                                fold + 64 + 3 * 64, eRW2 + 3 * 2048,
                                                eRb2 + 3 * 64, s5, N16);

  // ---- decoders (in place, top-down) ----
  k_dec_s<<<(N16 + 63) / 64, 256, 0, stream>>>(s5, s5, nullptr, mlpW + 0 * 4096, mlpb + 0 * 64,
                                               decW + 0 * 8192, decb + 0 * 64,
                                               fold + 320 + 0 * 128, N16);
  k_dec_s<<<(N8 + 63) / 64, 256, 0, stream>>>(s4, s5, inv16, mlpW + 1 * 4096, mlpb + 1 * 64,
                                              decW + 1 * 8192, decb + 1 * 64,
                                              fold + 320 + 1 * 128, N8);
  k_dec_s<<<(N4 + 63) / 64, 256, 0, stream>>>(s3, s4, inv8, mlpW + 2 * 4096, mlpb + 2 * 64,
                                              decW + 2 * 8192, decb + 2 * 64,
                                              fold + 320 + 2 * 128, N4);
  k_dec_s<<<(N2 + 63) / 64, 256, 0, stream>>>(s2, s3, inv4, mlpW + 3 * 4096, mlpb + 3 * 64,
                                              decW + 3 * 8192, decb + 3 * 64,
                                              fold + 320 + 3 * 128, N2);
  k_dec_s<<<(N1 + 63) / 64, 256, 0, stream>>>(s1, s2, inv2, mlpW + 4 * 4096, mlpb + 4 * 64,
                                              decW + 4 * 8192, decb + 4 * 64,
                                              fold + 320 + 4 * 128, N1);
}